// Round 3
// baseline (243.975 us; speedup 1.0000x reference)
//
#include <hip/hip_runtime.h>

// Paged attention decode, GQA: B=32, H=32, KVH=8 (G=4), D=128, pages of 16.
// R3: wave-autonomous flash-decoding. One wave per (b, kvh, part); no LDS,
// no barriers. K/V pages double-buffered in registers; QK^T reduced with
// shfl_xor over 16-lane d-groups; online softmax with shfl_xor over token
// groups; PV accumulate is in-lane. Partition = 128 tokens (8 pages).

constexpr int Dh   = 128;
constexpr int Gq   = 4;     // query heads per kv head
constexpr int KVH  = 8;
constexpr int Hq   = 32;
constexpr int Bb   = 32;
constexpr int MB   = 256;   // max pages per sequence
constexpr int PAGE = 16;
constexpr float SCALE = 0.08838834764831845f;

constexpr int NPARTS      = 32;
constexpr int PART_TOKENS = 128;                 // MB*PAGE / NPARTS
constexpr int PG_STRIDE   = PAGE * KVH * Dh;     // 16384 elements per page

// per-part workspace floats: acc[4][128] + m[4] + l[4]
constexpr int PART_STRIDE = Gq * Dh + 2 * Gq;    // 520

struct PageR { float4 a[4], b[4]; };             // 16 tokens x 8 floats / 64 lanes

__global__ __launch_bounds__(256, 2)
void attn_partial(const float* __restrict__ q,
                  const float* __restrict__ kc,
                  const float* __restrict__ vc,
                  const int*   __restrict__ bt,
                  const int*   __restrict__ cl,
                  float*       __restrict__ ws)
{
    const int wid  = blockIdx.x * 4 + (threadIdx.x >> 6);   // global wave id
    const int part = wid & (NPARTS - 1);
    const int bkv  = wid >> 5;
    const int kvh  = bkv & (KVH - 1);
    const int b    = bkv >> 3;

    const int ctx    = cl[b];
    const int pstart = part * PART_TOKENS;
    if (pstart >= ctx) return;                   // wave-uniform exit, no barriers
    const int n   = min(PART_TOKENS, ctx - pstart);
    const int npg = (n + PAGE - 1) >> 4;

    const int lane = threadIdx.x & 63;
    const int tl   = lane >> 4;                  // token-in-quad 0..3
    const int dc   = lane & 15;                  // d-chunk (8 floats)

    // Q fragments, pre-scaled: head g, dims [dc*8, dc*8+8)
    float4 qa[Gq], qb[Gq];
    {
        const float* qbase = q + (size_t)(b * Hq + kvh * Gq) * Dh + dc * 8;
        #pragma unroll
        for (int g = 0; g < Gq; ++g) {
            float4 x = *(const float4*)(qbase + g * Dh);
            float4 y = *(const float4*)(qbase + g * Dh + 4);
            qa[g] = make_float4(x.x * SCALE, x.y * SCALE, x.z * SCALE, x.w * SCALE);
            qb[g] = make_float4(y.x * SCALE, y.y * SCALE, y.z * SCALE, y.w * SCALE);
        }
    }

    const int* btrow = bt + b * MB + (pstart >> 4);
    // lane-invariant element offset inside a page: token tl part + kvh + d-chunk
    const int lane_off = tl * (KVH * Dh) + kvh * Dh + dc * 8;

    float4 accA[Gq], accB[Gq];
    float  m_run[Gq], l_run[Gq];
    #pragma unroll
    for (int g = 0; g < Gq; ++g) {
        accA[g] = make_float4(0.f, 0.f, 0.f, 0.f);
        accB[g] = make_float4(0.f, 0.f, 0.f, 0.f);
        m_run[g] = -1e30f;
        l_run[g] = 0.f;
    }

    auto LOAD = [&](PageR& K, PageR& V, int p) {
        const int phys = btrow[p];
        const float* kp = kc + (size_t)phys * PG_STRIDE + lane_off;
        const float* vp = vc + (size_t)phys * PG_STRIDE + lane_off;
        #pragma unroll
        for (int si = 0; si < 4; ++si) {         // token = si*4 + tl
            K.a[si] = *(const float4*)(kp + si * 4 * (KVH * Dh));
            K.b[si] = *(const float4*)(kp + si * 4 * (KVH * Dh) + 4);
            V.a[si] = *(const float4*)(vp + si * 4 * (KVH * Dh));
            V.b[si] = *(const float4*)(vp + si * 4 * (KVH * Dh) + 4);
        }
    };

    auto COMPUTE = [&](const PageR& K, const PageR& V, int p) {
        float s[4][Gq];
        #pragma unroll
        for (int si = 0; si < 4; ++si) {
            const bool valid = (p * PAGE + si * 4 + tl) < n;
            #pragma unroll
            for (int g = 0; g < Gq; ++g) {
                float t = K.a[si].x * qa[g].x + K.a[si].y * qa[g].y
                        + K.a[si].z * qa[g].z + K.a[si].w * qa[g].w
                        + K.b[si].x * qb[g].x + K.b[si].y * qb[g].y
                        + K.b[si].z * qb[g].z + K.b[si].w * qb[g].w;
                t += __shfl_xor(t, 1);
                t += __shfl_xor(t, 2);
                t += __shfl_xor(t, 4);
                t += __shfl_xor(t, 8);           // all 16 lanes hold the dot
                s[si][g] = valid ? t : -1e30f;
            }
        }
        #pragma unroll
        for (int g = 0; g < Gq; ++g) {
            float tm = fmaxf(fmaxf(s[0][g], s[1][g]), fmaxf(s[2][g], s[3][g]));
            tm = fmaxf(tm, __shfl_xor(tm, 16));
            tm = fmaxf(tm, __shfl_xor(tm, 32));  // max over the 16 tokens
            const float mn    = fmaxf(m_run[g], tm);
            const float alpha = __expf(m_run[g] - mn);
            m_run[g] = mn;
            const float p0 = __expf(s[0][g] - mn);
            const float p1 = __expf(s[1][g] - mn);
            const float p2 = __expf(s[2][g] - mn);
            const float p3 = __expf(s[3][g] - mn);
            float ls = p0 + p1 + p2 + p3;
            ls += __shfl_xor(ls, 16);
            ls += __shfl_xor(ls, 32);            // sum over the 16 tokens
            l_run[g] = l_run[g] * alpha + ls;
            // PV: in-lane, token si*4+tl matches V rows
            accA[g].x = fmaf(p3, V.a[3].x, fmaf(p2, V.a[2].x, fmaf(p1, V.a[1].x, fmaf(p0, V.a[0].x, accA[g].x * alpha))));
            accA[g].y = fmaf(p3, V.a[3].y, fmaf(p2, V.a[2].y, fmaf(p1, V.a[1].y, fmaf(p0, V.a[0].y, accA[g].y * alpha))));
            accA[g].z = fmaf(p3, V.a[3].z, fmaf(p2, V.a[2].z, fmaf(p1, V.a[1].z, fmaf(p0, V.a[0].z, accA[g].z * alpha))));
            accA[g].w = fmaf(p3, V.a[3].w, fmaf(p2, V.a[2].w, fmaf(p1, V.a[1].w, fmaf(p0, V.a[0].w, accA[g].w * alpha))));
            accB[g].x = fmaf(p3, V.b[3].x, fmaf(p2, V.b[2].x, fmaf(p1, V.b[1].x, fmaf(p0, V.b[0].x, accB[g].x * alpha))));
            accB[g].y = fmaf(p3, V.b[3].y, fmaf(p2, V.b[2].y, fmaf(p1, V.b[1].y, fmaf(p0, V.b[0].y, accB[g].y * alpha))));
            accB[g].z = fmaf(p3, V.b[3].z, fmaf(p2, V.b[2].z, fmaf(p1, V.b[1].z, fmaf(p0, V.b[0].z, accB[g].z * alpha))));
            accB[g].w = fmaf(p3, V.b[3].w, fmaf(p2, V.b[2].w, fmaf(p1, V.b[1].w, fmaf(p0, V.b[0].w, accB[g].w * alpha))));
        }
    };

    // page loop: manual even/odd double-buffer (static register names)
    PageR K0, V0, K1, V1;
    LOAD(K0, V0, 0);
    int p = 0;
    while (true) {
        if (p + 1 < npg) LOAD(K1, V1, p + 1);
        COMPUTE(K0, V0, p);
        ++p; if (p >= npg) break;
        if (p + 1 < npg) LOAD(K0, V0, p + 1);
        COMPUTE(K1, V1, p);
        ++p; if (p >= npg) break;
    }

    // reduce partial accumulators over the 4 token groups (tl)
    #pragma unroll
    for (int g = 0; g < Gq; ++g) {
        accA[g].x += __shfl_xor(accA[g].x, 16); accA[g].x += __shfl_xor(accA[g].x, 32);
        accA[g].y += __shfl_xor(accA[g].y, 16); accA[g].y += __shfl_xor(accA[g].y, 32);
        accA[g].z += __shfl_xor(accA[g].z, 16); accA[g].z += __shfl_xor(accA[g].z, 32);
        accA[g].w += __shfl_xor(accA[g].w, 16); accA[g].w += __shfl_xor(accA[g].w, 32);
        accB[g].x += __shfl_xor(accB[g].x, 16); accB[g].x += __shfl_xor(accB[g].x, 32);
        accB[g].y += __shfl_xor(accB[g].y, 16); accB[g].y += __shfl_xor(accB[g].y, 32);
        accB[g].z += __shfl_xor(accB[g].z, 16); accB[g].z += __shfl_xor(accB[g].z, 32);
        accB[g].w += __shfl_xor(accB[g].w, 16); accB[g].w += __shfl_xor(accB[g].w, 32);
    }

    float* wp = ws + ((size_t)bkv * NPARTS + part) * PART_STRIDE;
    #pragma unroll
    for (int g = 0; g < Gq; ++g) {
        if (tl == g) {
            *(float4*)(wp + g * Dh + dc * 8)     = accA[g];
            *(float4*)(wp + g * Dh + dc * 8 + 4) = accB[g];
        }
    }
    if (lane == 0) {
        #pragma unroll
        for (int g = 0; g < Gq; ++g) {
            wp[Gq * Dh + g]      = m_run[g];
            wp[Gq * Dh + Gq + g] = l_run[g];
        }
    }
}

__global__ __launch_bounds__(256, 4)
void attn_reduce(const float* __restrict__ ws,
                 const int*   __restrict__ cl,
                 float*       __restrict__ out)
{
    const int bkv = blockIdx.x;
    const int kvh = bkv & (KVH - 1);
    const int b   = bkv >> 3;
    const int ctx = cl[b];
    const int np  = min(NPARTS, (ctx + PART_TOKENS - 1) / PART_TOKENS);

    const int tid = threadIdx.x;
    const int g   = tid >> 6;
    const int d0  = (tid & 63) * 2;

    const float* base = ws + (size_t)bkv * NPARTS * PART_STRIDE;

    float m = -1e30f;
    for (int p = 0; p < np; ++p)
        m = fmaxf(m, base[p * PART_STRIDE + Gq * Dh + g]);

    float L = 0.f, ax = 0.f, ay = 0.f;
    for (int p = 0; p < np; ++p) {
        const float* bp = base + p * PART_STRIDE;
        const float c = __expf(bp[Gq * Dh + g] - m);
        L  += bp[Gq * Dh + Gq + g] * c;
        ax += bp[g * Dh + d0]     * c;
        ay += bp[g * Dh + d0 + 1] * c;
    }
    const float inv = 1.f / L;
    const size_t o = ((size_t)(b * Hq + kvh * Gq + g)) * Dh + d0;
    out[o]     = ax * inv;
    out[o + 1] = ay * inv;
}

extern "C" void kernel_launch(void* const* d_in, const int* in_sizes, int n_in,
                              void* d_out, int out_size, void* d_ws, size_t ws_size,
                              hipStream_t stream) {
    const float* q  = (const float*)d_in[0];
    const float* kc = (const float*)d_in[1];
    const float* vc = (const float*)d_in[2];
    const int*   bt = (const int*)d_in[3];
    const int*   cl = (const int*)d_in[4];
    float* out = (float*)d_out;
    float* ws  = (float*)d_ws;

    const int nwaves  = Bb * KVH * NPARTS;       // 8192
    const int nblocks = nwaves / 4;              // 4 waves per 256-thread block

    attn_partial<<<dim3(nblocks), dim3(256), 0, stream>>>(q, kc, vc, bt, cl, ws);
    attn_reduce<<<dim3(Bb * KVH), dim3(256), 0, stream>>>(ws, cl, out);
}

// Round 4
// 162.767 us; speedup vs baseline: 1.4989x; 1.4989x over previous
//
#include <hip/hip_runtime.h>

// Paged attention decode, GQA: B=32, H=32, KVH=8 (G=4), D=128, pages of 16.
// R4: full-page contiguous reads. One block per (b, part); the block serves
// ALL 8 kv heads (and their 4 query heads each), so every physical page is
// read exactly once, contiguously, by one block -> DRAM row locality.
// Thread t owns (kvh = t>>5, d-chunk = (t&31)*4). No LDS, no barriers:
// QK^T reduced by shfl_xor within 32-lane kvh groups; softmax group-uniform
// in-register; PV in-lane. Half-page (8-token) ping-pong double buffer.

constexpr int Dh   = 128;
constexpr int Gq   = 4;
constexpr int KVH  = 8;
constexpr int Hq   = 32;
constexpr int Bb   = 32;
constexpr int MB   = 256;
constexpr int PAGE = 16;
constexpr float SCALE = 0.08838834764831845f;

constexpr int NPARTS      = 64;
constexpr int PART_TOKENS = 64;                  // 4 pages per part
constexpr int PG_FLOATS   = PAGE * KVH * Dh;     // 16384 floats = 64 KB
constexpr int HALF_FLOATS = 8 * KVH * Dh;        // 8192 floats = 32 KB
constexpr int ROW_FLOATS  = KVH * Dh;            // 1024 floats per token

// per-(b,part) workspace floats: acc[32 heads][128] + m[32] + l[32]
constexpr int PART_STRIDE = Hq * Dh + 2 * Hq;    // 4160

struct HalfR { float4 k[8], v[8]; };             // 8 tokens, 4 floats each of K and V

__global__ __launch_bounds__(256, 2)
void attn_partial(const float* __restrict__ q,
                  const float* __restrict__ kc,
                  const float* __restrict__ vc,
                  const int*   __restrict__ bt,
                  const int*   __restrict__ cl,
                  float*       __restrict__ ws)
{
    const int part = blockIdx.x & (NPARTS - 1);
    const int b    = blockIdx.x >> 6;            // NPARTS = 64

    const int ctx    = cl[b];
    const int pstart = part * PART_TOKENS;
    if (pstart >= ctx) return;
    const int n   = min(PART_TOKENS, ctx - pstart);
    const int npg = (n + PAGE - 1) >> 4;
    const int TH  = npg * 2;                     // number of 8-token halves

    const int t      = threadIdx.x;              // 0..255
    const int kvh    = t >> 5;
    const int lane32 = t & 31;
    const int doff   = lane32 * 4;               // this thread's 4 dims

    // Q fragments, pre-scaled: head (kvh,g), dims [doff, doff+4)
    float4 qv[Gq];
    {
        const float* qbase = q + (size_t)(b * Hq + kvh * Gq) * Dh + doff;
        #pragma unroll
        for (int g = 0; g < Gq; ++g) {
            float4 x = *(const float4*)(qbase + g * Dh);
            qv[g] = make_float4(x.x * SCALE, x.y * SCALE, x.z * SCALE, x.w * SCALE);
        }
    }

    float4 acc[Gq];
    float  m_run[Gq], l_run[Gq];
    #pragma unroll
    for (int g = 0; g < Gq; ++g) {
        acc[g] = make_float4(0.f, 0.f, 0.f, 0.f);
        m_run[g] = -1e30f;
        l_run[g] = 0.f;
    }

    const int* btrow = bt + b * MB + (pstart >> 4);

    auto LOAD = [&](HalfR& H, int hh) {
        const int phys = btrow[hh >> 1];
        const size_t off = (size_t)phys * PG_FLOATS + (hh & 1) * HALF_FLOATS + t * 4;
        const float* kp = kc + off;
        const float* vp = vc + off;
        #pragma unroll
        for (int j = 0; j < 8; ++j) {            // token j of this half
            H.k[j] = *(const float4*)(kp + j * ROW_FLOATS);
            H.v[j] = *(const float4*)(vp + j * ROW_FLOATS);
        }
    };

    auto COMPUTE = [&](const HalfR& H, int hh) {
        const int base = (hh >> 1) * PAGE + (hh & 1) * 8;   // token base within part
        float s[8][Gq];
        #pragma unroll
        for (int j = 0; j < 8; ++j) {
            const bool vj = (base + j) < n;
            #pragma unroll
            for (int g = 0; g < Gq; ++g) {
                float d = H.k[j].x * qv[g].x + H.k[j].y * qv[g].y
                        + H.k[j].z * qv[g].z + H.k[j].w * qv[g].w;
                d += __shfl_xor(d, 1);
                d += __shfl_xor(d, 2);
                d += __shfl_xor(d, 4);
                d += __shfl_xor(d, 8);
                d += __shfl_xor(d, 16);          // full dot in all 32 lanes of kvh group
                s[j][g] = vj ? d : -1e30f;
            }
        }
        #pragma unroll
        for (int g = 0; g < Gq; ++g) {
            float tm = s[0][g];
            #pragma unroll
            for (int j = 1; j < 8; ++j) tm = fmaxf(tm, s[j][g]);
            const float mn    = fmaxf(m_run[g], tm);
            const float alpha = __expf(m_run[g] - mn);
            m_run[g] = mn;
            float p[8];
            #pragma unroll
            for (int j = 0; j < 8; ++j) p[j] = __expf(s[j][g] - mn);
            float ls = 0.f;
            #pragma unroll
            for (int j = 0; j < 8; ++j) ls += p[j];
            l_run[g] = l_run[g] * alpha + ls;
            float ax = acc[g].x * alpha, ay = acc[g].y * alpha,
                  az = acc[g].z * alpha, aw = acc[g].w * alpha;
            #pragma unroll
            for (int j = 0; j < 8; ++j) {
                ax = fmaf(p[j], H.v[j].x, ax);
                ay = fmaf(p[j], H.v[j].y, ay);
                az = fmaf(p[j], H.v[j].z, az);
                aw = fmaf(p[j], H.v[j].w, aw);
            }
            acc[g] = make_float4(ax, ay, az, aw);
        }
    };

    // half-page loop: manual even/odd double buffer (static register names)
    HalfR A, B;
    LOAD(A, 0);
    int hh = 0;
    while (true) {
        if (hh + 1 < TH) LOAD(B, hh + 1);
        COMPUTE(A, hh);
        ++hh; if (hh >= TH) break;
        if (hh + 1 < TH) LOAD(A, hh + 1);
        COMPUTE(B, hh);
        ++hh; if (hh >= TH) break;
    }

    // write partials: acc for heads (kvh*4+g), dims [doff, doff+4)
    float* wp = ws + (size_t)(b * NPARTS + part) * PART_STRIDE;
    #pragma unroll
    for (int g = 0; g < Gq; ++g)
        *(float4*)(wp + (kvh * Gq + g) * Dh + doff) = acc[g];
    if (lane32 == 0) {
        #pragma unroll
        for (int g = 0; g < Gq; ++g) {
            wp[Hq * Dh + kvh * Gq + g]      = m_run[g];
            wp[Hq * Dh + Hq + kvh * Gq + g] = l_run[g];
        }
    }
}

__global__ __launch_bounds__(256, 4)
void attn_reduce(const float* __restrict__ ws,
                 const int*   __restrict__ cl,
                 float*       __restrict__ out)
{
    const int b       = blockIdx.x >> 2;
    const int quarter = blockIdx.x & 3;
    const int tid     = threadIdx.x;
    const int h       = quarter * 8 + (tid >> 5);   // head 0..31
    const int doff    = (tid & 31) * 4;

    const int ctx = cl[b];
    const int np  = min(NPARTS, (ctx + PART_TOKENS - 1) / PART_TOKENS);

    const float* base = ws + (size_t)b * NPARTS * PART_STRIDE;

    float m = -1e30f;
    for (int p = 0; p < np; ++p)
        m = fmaxf(m, base[p * PART_STRIDE + Hq * Dh + h]);

    float L = 0.f;
    float ax = 0.f, ay = 0.f, az = 0.f, aw = 0.f;
    for (int p = 0; p < np; ++p) {
        const float* bp = base + p * PART_STRIDE;
        const float c = __expf(bp[Hq * Dh + h] - m);
        L += bp[Hq * Dh + Hq + h] * c;
        const float4 v = *(const float4*)(bp + h * Dh + doff);
        ax = fmaf(c, v.x, ax);
        ay = fmaf(c, v.y, ay);
        az = fmaf(c, v.z, az);
        aw = fmaf(c, v.w, aw);
    }
    const float inv = 1.f / L;
    float* op = out + (size_t)(b * Hq + h) * Dh + doff;
    *(float4*)op = make_float4(ax * inv, ay * inv, az * inv, aw * inv);
}

extern "C" void kernel_launch(void* const* d_in, const int* in_sizes, int n_in,
                              void* d_out, int out_size, void* d_ws, size_t ws_size,
                              hipStream_t stream) {
    const float* q  = (const float*)d_in[0];
    const float* kc = (const float*)d_in[1];
    const float* vc = (const float*)d_in[2];
    const int*   bt = (const int*)d_in[3];
    const int*   cl = (const int*)d_in[4];
    float* out = (float*)d_out;
    float* ws  = (float*)d_ws;

    attn_partial<<<dim3(Bb * NPARTS), dim3(256), 0, stream>>>(q, kc, vc, bt, cl, ws);
    attn_reduce<<<dim3(Bb * 4), dim3(256), 0, stream>>>(ws, cl, out);
}